// Round 11
// baseline (313.704 us; speedup 1.0000x reference)
//
#include <hip/hip_runtime.h>
#include <math.h>

// ---------------------------------------------------------------------------
// GraphSAGE fraud detector. CSR-gather aggregation + bf16 MFMA GEMMs.
// R27: dispatch-granularity fix. gather_mean_512 showed occupancy 40% with
// NO resource limit: 12500 x 4-row blocks @ ~4us = 205 blocks/us sustained
// dispatch -- the CP dispatch rate caps residency (Little's law: 820 blocks
// resident = 40%). Fix: 8 rows/wave -> 1563 blocks (35/us needed), blocks
// 8x longer, residency VGPR-limited. Same for the other tiny-block kernels:
// cvt3_hist grid-stride (1024 cvt + 512 hist blocks), bucket grid-stride
// (1024). Gather inner loop split: unmasked full batches + ONE masked tail
// batch (drops sel-mul + clamp on ~half the traffic; keeps R23's
// no-serial-tail). GEMMs/CSR = R26 exact (gemm2 at structural plateau:
// 5 schedule variants 66-70us, R26 61us; MfmaUtil 34%).
// Wf packing kept: off = ((((t*8+g)*4+nt)*4+quad)*16+cl)*8+j.
// MFMA 16x16x32 bf16: A-frag A[m=lane&15][k=quad*8+j]; C/D col=lane&15,
// row=quad*4+reg (m89/m97-verified layouts).
// ---------------------------------------------------------------------------

typedef __attribute__((ext_vector_type(8))) short bf16x8;   // 8 bf16, 4 VGPRs
typedef __attribute__((ext_vector_type(4))) float f32x4;

static inline int ceil_div(int a, int b) { return (a + b - 1) / b; }

__device__ inline float bf2f_lo(unsigned u) { return __builtin_bit_cast(float, u << 16); }
__device__ inline float bf2f_hi(unsigned u) { return __builtin_bit_cast(float, u & 0xffff0000u); }
__device__ inline unsigned f2bf(float f) {   // RNE round to bf16, bits in low 16
    unsigned u = __builtin_bit_cast(unsigned, f);
    u += 0x7fffu + ((u >> 16) & 1u);
    return u >> 16;
}

// async global->LDS, 16 B per lane; LDS dest = wave-uniform base + lane*16
#define GLOAD_LDS16(gp, lp)                                                   \
    __builtin_amdgcn_global_load_lds(                                         \
        (__attribute__((address_space(1))) void*)(gp),                        \
        (__attribute__((address_space(3))) void*)(lp), 16, 0, 0)

// ---------------- fused cvt(x, W1-pack, W2-pack) + deg histogram -----------
// Grid-stride both sections (R27): CVT_B blocks cover na4+nb4+nc4 float4s,
// HIST_B blocks cover E edges.

#define CVT_B  1024
#define HIST_B 512

__global__ __launch_bounds__(256) void cvt3_hist_kernel(
    const float* __restrict__ a, unsigned short* __restrict__ ao, int na4,
    const float* __restrict__ b, unsigned short* __restrict__ bo, int nb4,
    const float* __restrict__ c, unsigned short* __restrict__ co, int nc4,
    const int* __restrict__ dst, int* __restrict__ deg, int E) {
    if ((int)blockIdx.x < CVT_B) {
        const int total = na4 + nb4 + nc4;
        for (int i = blockIdx.x * 256 + threadIdx.x; i < total; i += CVT_B * 256) {
            if (i < na4) {                         // x -> xb (linear)
                float4 v = ((const float4*)a)[i];
                ushort4 o;
                o.x = (unsigned short)f2bf(v.x);
                o.y = (unsigned short)f2bf(v.y);
                o.z = (unsigned short)f2bf(v.z);
                o.w = (unsigned short)f2bf(v.w);
                ((ushort4*)ao)[i] = o;
            } else if (i < na4 + nb4) {            // W1 [512][256] -> Wf1 pack
                int kk = i - na4;
                float4 v = ((const float4*)b)[kk];
                ushort4 o;
                o.x = (unsigned short)f2bf(v.x);
                o.y = (unsigned short)f2bf(v.y);
                o.z = (unsigned short)f2bf(v.z);
                o.w = (unsigned short)f2bf(v.w);
                const int cc = kk >> 6;            // row (output col), 0..511
                const int kq = kk & 63;            // float4 within row (256 cols)
                const int t    = kq >> 3;          // k-tile of 32 (0..7)
                const int quad = (kq >> 1) & 3;
                const int j0   = (kq & 1) * 4;
                const int g  = cc >> 6, nt = (cc >> 4) & 3, cl = cc & 15;
                const size_t off =
                    ((((size_t)(t * 8 + g) * 4 + nt) * 4 + quad) * 16 + cl) * 8 + j0;
                *(ushort4*)(bo + off) = o;
            } else {                               // W2 [512][1024] -> Wf2 pack
                int kk = i - na4 - nb4;
                float4 v = ((const float4*)c)[kk];
                ushort4 o;
                o.x = (unsigned short)f2bf(v.x);
                o.y = (unsigned short)f2bf(v.y);
                o.z = (unsigned short)f2bf(v.z);
                o.w = (unsigned short)f2bf(v.w);
                const int cc = kk >> 8;            // row (output col), 0..511
                const int kq = kk & 255;           // float4 within row
                const int t    = kq >> 3;          // k-tile of 32 (0..31)
                const int quad = (kq >> 1) & 3;
                const int j0   = (kq & 1) * 4;
                const int g  = cc >> 6, nt = (cc >> 4) & 3, cl = cc & 15;
                const size_t off =
                    ((((size_t)(t * 8 + g) * 4 + nt) * 4 + quad) * 16 + cl) * 8 + j0;
                *(ushort4*)(co + off) = o;
            }
        }
    } else {
        for (int e = ((int)blockIdx.x - CVT_B) * 256 + threadIdx.x; e < E;
             e += HIST_B * 256)
            atomicAdd(&deg[dst[e]], 1);
    }
}

// ---------------- CSR build ----------------

// per-1024-chunk sums
__global__ __launch_bounds__(256) void chunk_reduce(const int* __restrict__ deg,
                                                    int* __restrict__ partial, int N) {
    int base = blockIdx.x * 1024;
    int s = 0;
    for (int i = threadIdx.x; i < 1024; i += 256) {
        int idx = base + i;
        if (idx < N) s += deg[idx];
    }
    #pragma unroll
    for (int off = 32; off; off >>= 1) s += __shfl_down(s, off);
    __shared__ int ws[4];
    if ((threadIdx.x & 63) == 0) ws[threadIdx.x >> 6] = s;
    __syncthreads();
    if (threadIdx.x == 0) partial[blockIdx.x] = ws[0] + ws[1] + ws[2] + ws[3];
}

// per-chunk exclusive scan + global offset (fused partial re-reduce);
// block 0 also writes rowstart[N] = total.
__global__ __launch_bounds__(256) void chunk_scan(const int* __restrict__ deg,
                                                  const int* __restrict__ partial,
                                                  int* __restrict__ rowstart,
                                                  int* __restrict__ cursor, int N, int P) {
    __shared__ int off_sh;
    __shared__ int ws[4];
    if (threadIdx.x < 64) {
        const int j = threadIdx.x;
        const int pv = (j < P) ? partial[j] : 0;
        int tot = pv;
        #pragma unroll
        for (int o = 1; o < 64; o <<= 1) tot += __shfl_xor(tot, o);
        int mv = (j < (int)blockIdx.x) ? pv : 0;
        #pragma unroll
        for (int o = 1; o < 64; o <<= 1) mv += __shfl_xor(mv, o);
        if (j == 0) {
            off_sh = mv;
            if (blockIdx.x == 0) rowstart[N] = tot;
        }
    }
    __syncthreads();

    int base = blockIdx.x * 1024 + threadIdx.x * 4;
    int v[4];
    #pragma unroll
    for (int j = 0; j < 4; ++j) {
        int i = base + j;
        v[j] = (i < N) ? deg[i] : 0;
    }
    int mysum = v[0] + v[1] + v[2] + v[3];
    int incl = mysum;
    int lane = threadIdx.x & 63, wave = threadIdx.x >> 6;
    #pragma unroll
    for (int off = 1; off < 64; off <<= 1) {
        int t = __shfl_up(incl, off);
        if (lane >= off) incl += t;
    }
    if (lane == 63) ws[wave] = incl;
    __syncthreads();
    int run = off_sh + incl - mysum;
    for (int w = 0; w < wave; ++w) run += ws[w];
    #pragma unroll
    for (int j = 0; j < 4; ++j) {
        int i = base + j;
        if (i < N) { rowstart[i] = run; cursor[i] = run; }
        run += v[j];
    }
}

// grid-stride (R27)
__global__ __launch_bounds__(256) void bucket_kernel(const int* __restrict__ src,
                                                     const int* __restrict__ dst,
                                                     int* __restrict__ cursor,
                                                     int* __restrict__ ebuf, int E) {
    for (int e = blockIdx.x * 256 + threadIdx.x; e < E; e += gridDim.x * 256) {
        int pos = atomicAdd(&cursor[dst[e]], 1);
        ebuf[pos] = src[e];
    }
}

// ---------------- gather means (R27: 8 rows/wave, split batches) -----------

#define GROWS 8   // rows per wave

// one wave per row-group; bf16 xb [N,128] -> bf16 mean [N,128]; fp32 accum.
__global__ __launch_bounds__(256) void gather_mean_128(
    const int* __restrict__ rowstart, const int* __restrict__ ebuf,
    const unsigned* __restrict__ featb, unsigned* __restrict__ outb, int N) {
    const int gw   = (blockIdx.x * 256 + threadIdx.x) >> 6;
    const int lane = threadIdx.x & 63;
    const int r0   = gw * GROWS;
    if (r0 >= N) return;
    const int rend = (r0 + GROWS < N) ? r0 + GROWS : N;
    for (int row = r0; row < rend; ++row) {
        const int e0 = rowstart[row], e1 = rowstart[row + 1];
        float ax = 0.0f, ay = 0.0f;
        int i = e0;
        for (; i + 8 <= e1; i += 8) {        // full batches: unmasked
            int idx[8];
            #pragma unroll
            for (int u = 0; u < 8; ++u) idx[u] = ebuf[i + u];
            unsigned v[8];
            #pragma unroll
            for (int u = 0; u < 8; ++u)
                v[u] = featb[(size_t)idx[u] * 64 + lane];
            #pragma unroll
            for (int u = 0; u < 8; ++u) {
                ax += bf2f_lo(v[u]);
                ay += bf2f_hi(v[u]);
            }
        }
        if (i < e1) {                        // one masked tail batch
            int idx[8];
            #pragma unroll
            for (int u = 0; u < 8; ++u) {
                int t = i + u;
                idx[u] = ebuf[t < e1 ? t : e1 - 1];
            }
            unsigned v[8];
            #pragma unroll
            for (int u = 0; u < 8; ++u)
                v[u] = featb[(size_t)idx[u] * 64 + lane];
            #pragma unroll
            for (int u = 0; u < 8; ++u) {
                const float s = (i + u < e1) ? 1.0f : 0.0f;
                ax += s * bf2f_lo(v[u]);
                ay += s * bf2f_hi(v[u]);
            }
        }
        const float inv = 1.0f / fmaxf((float)(e1 - e0), 1.0f);
        outb[(size_t)row * 64 + lane] = f2bf(ax * inv) | (f2bf(ay * inv) << 16);
    }
}

// one wave per row-group; bf16 feat [N,512] -> bf16 mean [N,512]; fp32 accum.
__global__ __launch_bounds__(256) void gather_mean_512(
    const int* __restrict__ rowstart, const int* __restrict__ ebuf,
    const unsigned short* __restrict__ featb,
    unsigned short* __restrict__ outb, int N) {
    const int gw   = (blockIdx.x * 256 + threadIdx.x) >> 6;
    const int lane = threadIdx.x & 63;
    const int r0   = gw * GROWS;
    if (r0 >= N) return;
    const int rend = (r0 + GROWS < N) ? r0 + GROWS : N;
    const uint4* base = (const uint4*)featb;     // 512 bf16/row = 64 uint4/row
    for (int row = r0; row < rend; ++row) {
        const int e0 = rowstart[row], e1 = rowstart[row + 1];
        float a[8] = {0, 0, 0, 0, 0, 0, 0, 0};
        int i = e0;
        for (; i + 8 <= e1; i += 8) {        // full batches: unmasked
            int idx[8];
            #pragma unroll
            for (int u = 0; u < 8; ++u) idx[u] = ebuf[i + u];
            uint4 v[8];
            #pragma unroll
            for (int u = 0; u < 8; ++u)
                v[u] = base[(size_t)idx[u] * 64 + lane];
            #pragma unroll
            for (int u = 0; u < 8; ++u) {
                a[0] += bf2f_lo(v[u].x); a[1] += bf2f_hi(v[u].x);
                a[2] += bf2f_lo(v[u].y); a[3] += bf2f_hi(v[u].y);
                a[4] += bf2f_lo(v[u].z); a[5] += bf2f_hi(v[u].z);
                a[6] += bf2f_lo(v[u].w); a[7] += bf2f_hi(v[u].w);
            }
        }
        if (i < e1) {                        // one masked tail batch
            int idx[8];
            #pragma unroll
            for (int u = 0; u < 8; ++u) {
                int t = i + u;
                idx[u] = ebuf[t < e1 ? t : e1 - 1];
            }
            uint4 v[8];
            #pragma unroll
            for (int u = 0; u < 8; ++u)
                v[u] = base[(size_t)idx[u] * 64 + lane];
            #pragma unroll
            for (int u = 0; u < 8; ++u) {
                const float s = (i + u < e1) ? 1.0f : 0.0f;
                a[0] += s * bf2f_lo(v[u].x); a[1] += s * bf2f_hi(v[u].x);
                a[2] += s * bf2f_lo(v[u].y); a[3] += s * bf2f_hi(v[u].y);
                a[4] += s * bf2f_lo(v[u].z); a[5] += s * bf2f_hi(v[u].z);
                a[6] += s * bf2f_lo(v[u].w); a[7] += s * bf2f_hi(v[u].w);
            }
        }
        const float inv = 1.0f / fmaxf((float)(e1 - e0), 1.0f);
        uint4 o;
        o.x = f2bf(a[0] * inv) | (f2bf(a[1] * inv) << 16);
        o.y = f2bf(a[2] * inv) | (f2bf(a[3] * inv) << 16);
        o.z = f2bf(a[4] * inv) | (f2bf(a[5] * inv) << 16);
        o.w = f2bf(a[6] * inv) | (f2bf(a[7] * inv) << 16);
        ((uint4*)outb)[(size_t)row * 64 + lane] = o;
    }
}

// ---------------- shared breg-GEMM machinery (R26: 64x512 block) -----------
// 512 thr = 8 waves 1x8; wave w owns cols w*64..+64, all 64 rows; BK=32.
// A staged in PAIRS of K-tiles (8KB: wave w writes bytes w*1024, covering
// tile kt+(w>>2), rows (w&3)*16+(l>>2), slot l&3) into 3 bufs x 8KB.
// B per wave from fragment-packed Wf (4 x 1KB dwordx4), bq double-buffered.
// Phase p: GATE(gs); barrier; RDA(p); MFMA(bq[p&1]); LDB(p+2); [STGP(p+4)].
// Group-aligned gates: drain whole issue-groups (order-invariant).

#define STGP(kt, SPL) do {                                                     \
    const int _ktw = (kt) + (w >> 2);                                          \
    const unsigned short* _p = (_ktw < (SPL))                                  \
        ? (A0 + (_ktw << 5)) : (A1 + ((_ktw - (SPL)) << 5));                   \
    GLOAD_LDS16(_p + offA, lds + (((kt) >> 1) % 3) * 8192 + w * 1024);         \
} while (0)

#define LDBg(kt, bqr) do {                                                     \
    _Pragma("unroll")                                                          \
    for (int _n = 0; _n < 4; ++_n)                                             \
        bqr[_n] = *(const bf16x8*)(W +                                         \
            (((size_t)(kt) * 8 + gB) * 4 + _n) * 512 + l * 8);                 \
} while (0)

#define RDAp(p) do {                                                           \
    _Pragma("unroll")                                                          \
    for (int _m = 0; _m < 4; ++_m)                                             \
        af[_m] = *(const bf16x8*)(lds + (((p) >> 1) % 3) * 8192 +              \
                  ((p) & 1) * 4096 + aoff + _m * 1024);                        \
} while (0)

#define MMg(bqr) do {                                                          \
    _Pragma("unroll")                                                          \
    for (int _m = 0; _m < 4; ++_m)                                             \
        _Pragma("unroll")                                                      \
        for (int _n = 0; _n < 4; ++_n)                                         \
            acc[_m][_n] = __builtin_amdgcn_mfma_f32_16x16x32_bf16(             \
                af[_m], bqr[_n], acc[_m][_n], 0, 0, 0);                        \
} while (0)

#define PH(p, bqr, gs, stg, ldb, SPL) do {                                     \
    __builtin_amdgcn_sched_barrier(0);                                         \
    asm volatile("s_waitcnt vmcnt(" gs ")" ::: "memory");                      \
    __builtin_amdgcn_s_barrier();                                              \
    __builtin_amdgcn_sched_barrier(0);                                         \
    RDAp(p);                                                                   \
    __builtin_amdgcn_s_setprio(1);                                             \
    MMg(bqr);                                                                  \
    __builtin_amdgcn_s_setprio(0);                                             \
    if (ldb) LDBg((p) + 2, bqr);                                               \
    if (stg) STGP((p) + 4, SPL);                                               \
} while (0)

// common prelude: XCD swizzle decode, addresses, acc init
#define BREG_PRELUDE(STR)                                                      \
    const int nwg  = (N + 63) >> 6;                                            \
    const int orig = blockIdx.x;                                               \
    const int xcd = orig & 7, lnum = orig >> 3;                                \
    const int q = nwg >> 3, r = nwg & 7;                                       \
    const int virt = (xcd < r ? xcd * (q + 1)                                  \
                              : r * (q + 1) + (xcd - r) * q) + lnum;           \
    const int row0 = virt << 6;                                                \
    const int tid = threadIdx.x;                                               \
    const int w = tid >> 6, l = tid & 63;                                      \
    const int cl = l & 15, quad = l >> 4;                                      \
    const int gB = w;                                                          \
    const int c_log = (((l & 3) ^ ((l >> 3) & 3))) * 8;                        \
    int ra = row0 + (w & 3) * 16 + (l >> 2);                                   \
    if (ra > N - 1) ra = N - 1;                                                \
    const size_t offA = (size_t)ra * (STR) + c_log;                            \
    const int swz  = ((cl >> 1) & 3) << 4;                                     \
    const int aoff = (cl * 64 + quad * 16) ^ swz;                              \
    f32x4 acc[4][4];                                                           \
    _Pragma("unroll")                                                          \
    for (int mt = 0; mt < 4; ++mt)                                             \
        _Pragma("unroll")                                                      \
        for (int nt = 0; nt < 4; ++nt)                                         \
            acc[mt][nt] = (f32x4){0.f, 0.f, 0.f, 0.f};                         \
    bf16x8 af[4], bqA[4], bqB[4];

// ---------------- layer-1: K=256 (KT=8) -> h1b bf16 ------------------------
__global__ __launch_bounds__(512, 4) void gemm1_breg(
    const unsigned short* __restrict__ A0,   // xb  [N,128] bf16
    const unsigned short* __restrict__ A1,   // n1b [N,128] bf16
    const unsigned short* __restrict__ W,    // Wf1 fragment-packed [512*256]
    const float* __restrict__ b,             // b1 [512]
    unsigned short* __restrict__ outb,       // h1b [N,512] bf16
    int N)
{
    __shared__ char lds[24576];              // A: 3 x 8KB (pair bufs)
    BREG_PRELUDE(128)

    STGP(0, 4); LDBg(0, bqA);
    STGP(2, 4); LDBg(1, bqB);

    PH(0, bqA, "5", 1, 1, 4);   // stage pair(4,5)
    PH(1, bqB, "5", 0, 1, 4);
    PH(2, bqA, "4", 1, 1, 4);   // stage pair(6,7)
    PH(3, bqB, "5", 0, 1, 4);
    PH(4, bqA, "4", 0, 1, 4);
    PH(5, bqB, "4", 0, 1, 4);
    PH(6, bqA, "4", 0, 0, 4);
    PH(7, bqB, "0", 0, 0, 4);

    // epilogue: ReLU + bias, store bf16 (wave-private cols)
    #pragma unroll
    for (int nt = 0; nt < 4; ++nt) {
        const int colx = w * 64 + nt * 16 + cl;
        const float bb = b[colx];
        #pragma unroll
        for (int mt = 0; mt < 4; ++mt) {
            #pragma unroll
            for (int rr = 0; rr < 4; ++rr) {
                const int row = row0 + mt * 16 + quad * 4 + rr;
                if (row < N)
                    outb[(size_t)row * 512 + colx] =
                        (unsigned short)f2bf(fmaxf(acc[mt][nt][rr] + bb, 0.0f));
            }
        }
    }
}

// ---------------- layer-2: K=1024 (KT=32), fused head -> out ---------------
__global__ __launch_bounds__(512, 4) void gemm2_breg(
    const unsigned short* __restrict__ A0,   // h1b [N,512] bf16
    const unsigned short* __restrict__ A1,   // n2b [N,512] bf16
    const unsigned short* __restrict__ W,    // Wf2 fragment-packed [512*1024]
    const float* __restrict__ b,             // b2 [512]
    const float* __restrict__ Wo,            // [512]
    const float* __restrict__ bo,            // [1]
    float* __restrict__ out,                 // [N] sigmoid output
    int N)
{
    __shared__ char lds[24576];              // A: 3 x 8KB (pair bufs)
    BREG_PRELUDE(512)

    STGP(0, 16); LDBg(0, bqA);
    STGP(2, 16); LDBg(1, bqB);

    PH(0, bqA, "5", 1, 1, 16);
    PH(1, bqB, "5", 0, 1, 16);
    #pragma unroll
    for (int p = 2; p < 28; p += 2) {
        PH(p,     bqA, "4", (p <= 26), 1, 16);
        PH(p + 1, bqB, "5", 0,         1, 16);
    }
    PH(28, bqA, "4", 0, 1, 16);
    PH(29, bqB, "4", 0, 1, 16);
    PH(30, bqA, "4", 0, 0, 16);
    PH(31, bqB, "0", 0, 0, 16);

    // epilogue: per-wave partial (ReLU + Wo dot), cross-wave LDS reduce,
    // sigmoid, direct store. ls uses bytes 0..2047 (phase-31 reads live in
    // 4096..8191 of buf0; no overlap; all waves passed barrier 31 so
    // phase-30 reads of bytes 0..4095 have retired).
    float bv[4], wv[4];
    #pragma unroll
    for (int nt = 0; nt < 4; ++nt) {
        const int colx = w * 64 + nt * 16 + cl;
        bv[nt] = b[colx];
        wv[nt] = Wo[colx];
    }
    float* ls = (float*)lds;                 // [64 rows][8 waves]
    #pragma unroll
    for (int mt = 0; mt < 4; ++mt) {
        #pragma unroll
        for (int rr = 0; rr < 4; ++rr) {
            float s = 0.0f;
            #pragma unroll
            for (int nt = 0; nt < 4; ++nt)
                s += fmaxf(acc[mt][nt][rr] + bv[nt], 0.0f) * wv[nt];
            s += __shfl_xor(s, 1);
            s += __shfl_xor(s, 2);
            s += __shfl_xor(s, 4);
            s += __shfl_xor(s, 8);
            if (cl == 0) ls[(mt * 16 + quad * 4 + rr) * 8 + w] = s;
        }
    }
    __syncthreads();
    if (tid < 64) {
        float s = 0.0f;
        #pragma unroll
        for (int w8 = 0; w8 < 8; ++w8) s += ls[tid * 8 + w8];
        const int row = row0 + tid;
        if (row < N) out[row] = 1.0f / (1.0f + expf(-(s + bo[0])));
    }
}

extern "C" void kernel_launch(void* const* d_in, const int* in_sizes, int n_in,
                              void* d_out, int out_size, void* d_ws, size_t ws_size,
                              hipStream_t stream) {
    const float* x  = (const float*)d_in[0];
    const int*   ei = (const int*)d_in[1];
    const float* W1 = (const float*)d_in[2];
    const float* b1 = (const float*)d_in[3];
    const float* W2 = (const float*)d_in[4];
    const float* b2 = (const float*)d_in[5];
    const float* Wo = (const float*)d_in[6];
    const float* bo = (const float*)d_in[7];
    float* out = (float*)d_out;

    const int N = in_sizes[0] / 128;   // 50000
    const int E = in_sizes[1] / 2;     // 400000
    const int* src = ei;
    const int* dst = ei + E;

    char* ws = (char*)d_ws;
    size_t off = 0;
    auto alloc = [&](size_t bytes) {
        void* p = ws + off;
        off += (bytes + 255) & ~(size_t)255;
        return p;
    };
    int* deg      = (int*)alloc((size_t)N * 4);
    int* rowstart = (int*)alloc((size_t)(N + 1) * 4);
    int* cursor   = (int*)alloc((size_t)N * 4);
    int* partial  = (int*)alloc((size_t)64 * 4);
    int* ebuf     = (int*)alloc((size_t)E * 4);
    unsigned short* xb  = (unsigned short*)alloc((size_t)N * 128 * 2);
    unsigned short* W1b = (unsigned short*)alloc((size_t)512 * 256 * 2);    // Wf1
    unsigned short* W2b = (unsigned short*)alloc((size_t)512 * 1024 * 2);   // Wf2
    unsigned short* n1b = (unsigned short*)alloc((size_t)N * 128 * 2);
    unsigned short* h1b = (unsigned short*)alloc((size_t)N * 512 * 2);
    unsigned short* n2b = (unsigned short*)alloc((size_t)N * 512 * 2);
    (void)ws_size; (void)n_in; (void)out_size;

    hipMemsetAsync(deg, 0, (size_t)N * 4, stream);

    // fused: cvt x (linear) + W1/W2 (fragment-pack) -> bf16  +  deg histogram
    const int na4 = N * 128 / 4, nb4 = 512 * 256 / 4, nc4 = 512 * 1024 / 4;
    cvt3_hist_kernel<<<CVT_B + HIST_B, 256, 0, stream>>>(
        x, xb, na4, W1, W1b, nb4, W2, W2b, nc4, dst, deg, E);

    // CSR build (reduce + fused scan)
    const int P = ceil_div(N, 1024);   // 49
    chunk_reduce<<<P, 256, 0, stream>>>(deg, partial, N);
    chunk_scan<<<P, 256, 0, stream>>>(deg, partial, rowstart, cursor, N, P);
    bucket_kernel<<<1024, 256, 0, stream>>>(src, dst, cursor, ebuf, E);

    const int g2 = ceil_div(N, 64);                 // 782 blocks (64-row tiles)
    const int gg = ceil_div(N, 4 * GROWS);          // 1563 gather blocks

    // layer 1: gather + breg GEMM (K=256)
    gather_mean_128<<<gg, 256, 0, stream>>>(rowstart, ebuf,
                                            (const unsigned*)xb, (unsigned*)n1b, N);
    gemm1_breg<<<g2, 512, 0, stream>>>(xb, n1b, W1b, b1, h1b, N);

    // layer 2 + fused head: gather + breg GEMM (K=1024) -> out directly
    gather_mean_512<<<gg, 256, 0, stream>>>(rowstart, ebuf, h1b, n2b, N);
    gemm2_breg<<<g2, 512, 0, stream>>>(h1b, n2b, W2b, b2, Wo, bo, out, N);
}